// Round 8
// baseline (238.798 us; speedup 1.0000x reference)
//
#include <hip/hip_runtime.h>
#include <hip/hip_bf16.h>
#include <stdint.h>

#define E_ 8
#define H_ 1024
#define I_ 2816
#define T_ 512

typedef __attribute__((ext_vector_type(4))) float f32x4;
typedef __attribute__((ext_vector_type(8))) short short8;

typedef __attribute__((address_space(1))) const unsigned GAS;
typedef __attribute__((address_space(3))) unsigned LAS;

__device__ __forceinline__ void dma16(const void* g, void* l) {
    __builtin_amdgcn_global_load_lds((GAS*)g, (LAS*)l, 16, 0, 0);
}
__device__ __forceinline__ unsigned short f2bf(float f) {   // RNE
    return __builtin_bit_cast(unsigned short, __float2bfloat16(f));
}
__device__ __forceinline__ uint32_t pack_rne(float lo, float hi) {
    return (uint32_t)f2bf(lo) | ((uint32_t)f2bf(hi) << 16);
}
// weights hold exact e4m3 values -> bf16 truncation is exact
__device__ __forceinline__ uint32_t pack_trunc(float lo, float hi) {
    return (__builtin_bit_cast(uint32_t, hi) & 0xFFFF0000u) |
           (__builtin_bit_cast(uint32_t, lo) >> 16);
}

#define VM6() asm volatile("s_waitcnt vmcnt(6)" ::: "memory")
#define VM4() asm volatile("s_waitcnt vmcnt(4)" ::: "memory")
#define VM0() asm volatile("s_waitcnt vmcnt(0)" ::: "memory")

// ---- routing + x->bf16 conversion (fused) ----
__global__ __launch_bounds__(256) void route_cvt(const float* __restrict__ x,
                                                 const int* __restrict__ idx,
                                                 int* __restrict__ counts,
                                                 int* __restrict__ bucket,
                                                 unsigned short* __restrict__ xg) {
    int tid = threadIdx.x;
    if (blockIdx.x == 0) {
        if (tid < E_) counts[tid] = 0;
        for (int i = tid; i < E_ * T_; i += 256) bucket[i] = 0;
        __syncthreads();
#pragma unroll
        for (int k = 0; k < 2; ++k) {
            int t = tid + k * 256;
            int e = idx[t];
            int pos = atomicAdd(counts + e, 1);
            bucket[e * T_ + pos] = t;
        }
    }
    int unit = blockIdx.x * 256 + tid;           // 65536 units of 8 elems
    const float* xp = x + (size_t)unit * 8;
    float4 a = *(const float4*)xp, b = *(const float4*)(xp + 4);
    uint4 o = make_uint4(pack_rne(a.x, a.y), pack_rne(a.z, a.w),
                         pack_rne(b.x, b.y), pack_rne(b.z, b.w));
    *(uint4*)(xg + (size_t)unit * 8) = o;
}

// ---- GEMM1: 128 tok x 32 feat (64 w-rows), BK=32, 32 steps, depth-3 DMA ----
// LDS: A bf16 3x8KB @0 ; B f32 3x8KB @24KB ; tok @48KB
__global__ __launch_bounds__(256) void gemm1(const unsigned short* __restrict__ xg,
                                             const float* __restrict__ wgu,
                                             const float* __restrict__ sgu_p,
                                             const int* __restrict__ counts,
                                             const int* __restrict__ bucket,
                                             __hip_bfloat16* __restrict__ hbuf) {
    int e = blockIdx.x >> 2, mt = blockIdx.x & 3;
    int cnt = counts[e];
    if (mt * 128 >= cnt) return;
    int f0 = blockIdx.y * 32;

    __shared__ __align__(16) char smem[48 * 1024 + 512];
    int* tok = (int*)(smem + 48 * 1024);
    int tid = threadIdx.x, w = tid >> 6, lane = tid & 63;
    int r16 = lane & 15, kg = lane >> 4;

    if (tid < 128) tok[tid] = bucket[e * T_ + mt * 128 + tid];
    __syncthreads();

    // A: no swizzle needed (compute reads cover full rows). 2 dma/wave/step.
    const char* xb = (const char*)xg;
    const char* srcA[2]; char* dstA[2];
#pragma unroll
    for (int i = 0; i < 2; ++i) {
        int gi = w * 2 + i;                       // instr 0..7
        int row = gi * 16 + (lane >> 2), sl = lane & 3;
        srcA[i] = xb + (size_t)tok[row] * 2048 + sl * 16;
        dstA[i] = smem + gi * 1024;
    }
    // B: 64 rows (32 gate + 32 up) x 128B/step, slot ^ (row&7) pre-swizzle
    const char* wg_e = (const char*)wgu + (size_t)e * (2 * (size_t)I_ * H_ * 4);
    const char* srcB[2]; char* dstB[2];
#pragma unroll
    for (int i = 0; i < 2; ++i) {
        int gi = w * 2 + i;                       // instr 0..7
        int row = gi * 8 + (lane >> 3), sl = lane & 7;
        int wr = (row < 32) ? (f0 + row) : (I_ + f0 + row - 32);
        srcB[i] = wg_e + (size_t)wr * 4096 + ((sl ^ (row & 7)) * 16);
        dstB[i] = smem + 24 * 1024 + gi * 1024;
    }

#define G1I(s, b) do {                                                               \
    _Pragma("unroll")                                                                \
    for (int i = 0; i < 2; ++i) dma16(srcA[i] + (size_t)(s) * 64,  dstA[i] + (b) * 8192); \
    _Pragma("unroll")                                                                \
    for (int i = 0; i < 2; ++i) dma16(srcB[i] + (size_t)(s) * 128, dstB[i] + (b) * 8192); } while (0)

    G1I(0, 0);
    G1I(1, 1);

    f32x4 acc[8];
#pragma unroll
    for (int m = 0; m < 8; ++m) acc[m] = (f32x4){0, 0, 0, 0};

    for (int t = 0; t < 32; ++t) {
        if (t < 30) { VM4(); } else { VM0(); }
        __builtin_amdgcn_sched_barrier(0);
        __builtin_amdgcn_s_barrier();
        if (t + 2 < 32) G1I(t + 2, (t + 2) % 3);
        const char* Ab = smem + (t % 3) * 8192;
        const char* Bb = smem + 24 * 1024 + (t % 3) * 8192;
        int br = w * 16 + r16;
        float4 b0 = *(const float4*)(Bb + br * 128 + (((2 * kg)     ^ (br & 7)) * 16));
        float4 b1 = *(const float4*)(Bb + br * 128 + (((2 * kg + 1) ^ (br & 7)) * 16));
        uint4 bu = make_uint4(pack_trunc(b0.x, b0.y), pack_trunc(b0.z, b0.w),
                              pack_trunc(b1.x, b1.y), pack_trunc(b1.z, b1.w));
        short8 B = __builtin_bit_cast(short8, bu);
#pragma unroll
        for (int m = 0; m < 8; ++m) {
            short8 A = *(const short8*)(Ab + (m * 16 + r16) * 64 + kg * 16);
            acc[m] = __builtin_amdgcn_mfma_f32_16x16x32_bf16(A, B, acc[m], 0, 0, 0);
        }
    }
    __syncthreads();                              // vmcnt already 0; reuse LDS

    // epilogue: waves 2,3 (up rows) export u*s; waves 0,1 (gate) fuse silu
    float sgu = sgu_p[0];
    float* ex = (float*)smem;
    if (w >= 2) {
        float* dst = ex + (w - 2) * 2048;
#pragma unroll
        for (int m = 0; m < 8; ++m)
#pragma unroll
            for (int j = 0; j < 4; ++j)
                dst[(m * 16 + kg * 4 + j) * 16 + r16] = acc[m][j] * sgu;
    }
    __syncthreads();
    if (w < 2) {
        const float* src = ex + w * 2048;
#pragma unroll
        for (int m = 0; m < 8; ++m)
#pragma unroll
            for (int j = 0; j < 4; ++j) {
                int tr = m * 16 + kg * 4 + j;
                int pos = mt * 128 + tr;
                if (pos < cnt) {
                    float g = acc[m][j] * sgu;
                    float u = src[tr * 16 + r16];
                    float hv = (g / (1.f + __expf(-g))) * u;
                    hbuf[(size_t)tok[tr] * I_ + f0 + w * 16 + r16] = __float2bfloat16(hv);
                }
            }
    }
}

// ---- GEMM2: 128 tok x 32 hcols, BK=64 over I, 44 steps, depth-3 DMA ----
// LDS: A bf16 3x16KB @0 ; B f32 3x8KB @48KB ; tok @72KB
__global__ __launch_bounds__(256) void gemm2(const __hip_bfloat16* __restrict__ hbuf,
                                             const float* __restrict__ wd,
                                             const float* __restrict__ sd_p,
                                             const int* __restrict__ counts,
                                             const int* __restrict__ bucket,
                                             float* __restrict__ out) {
    int e = blockIdx.x >> 2, mt = blockIdx.x & 3;
    int cnt = counts[e];
    if (mt * 128 >= cnt) return;
    int h0 = blockIdx.y * 32;

    __shared__ __align__(16) char smem[72 * 1024 + 512];
    int* tok = (int*)(smem + 72 * 1024);
    int tid = threadIdx.x, w = tid >> 6, lane = tid & 63;
    int r16 = lane & 15, kg = lane >> 4;
    int mg = w >> 1, ng = w & 1;

    if (tid < 128) tok[tid] = bucket[e * T_ + mt * 128 + tid];
    __syncthreads();

    // A (h bf16): 128 rows x 128B/step, slot ^ (row&7); 4 dma/wave/step
    const char* hb = (const char*)hbuf;
    const char* srcA[4]; char* dstA[4];
#pragma unroll
    for (int i = 0; i < 4; ++i) {
        int gi = w * 4 + i;                       // 0..15
        int row = gi * 8 + (lane >> 3), sl = lane & 7;
        srcA[i] = hb + (size_t)tok[row] * 5632 + ((sl ^ (row & 7)) * 16);
        dstA[i] = smem + gi * 1024;
    }
    // B (w_d f32): 32 rows x 256B/step, slot ^ (row&15); 2 dma/wave/step
    const char* wd_e = (const char*)wd + (size_t)e * ((size_t)H_ * I_ * 4);
    const char* srcB[2]; char* dstB[2];
#pragma unroll
    for (int i = 0; i < 2; ++i) {
        int gi = w * 2 + i;                       // 0..7
        int row = gi * 4 + (lane >> 4), sl = lane & 15;
        srcB[i] = wd_e + (size_t)(h0 + row) * 11264 + ((sl ^ (row & 15)) * 16);
        dstB[i] = smem + 48 * 1024 + gi * 1024;
    }

#define G2I(s, b) do {                                                                \
    _Pragma("unroll")                                                                 \
    for (int i = 0; i < 4; ++i) dma16(srcA[i] + (size_t)(s) * 128, dstA[i] + (b) * 16384); \
    _Pragma("unroll")                                                                 \
    for (int i = 0; i < 2; ++i) dma16(srcB[i] + (size_t)(s) * 256, dstB[i] + (b) * 8192);  } while (0)

    G2I(0, 0);
    G2I(1, 1);

    f32x4 acc[4];
#pragma unroll
    for (int m = 0; m < 4; ++m) acc[m] = (f32x4){0, 0, 0, 0};

    for (int t = 0; t < 44; ++t) {
        if (t < 42) { VM6(); } else { VM0(); }
        __builtin_amdgcn_sched_barrier(0);
        __builtin_amdgcn_s_barrier();
        if (t + 2 < 44) G2I(t + 2, (t + 2) % 3);
        const char* Ab = smem + (t % 3) * 16384;
        const char* Bb = smem + 48 * 1024 + (t % 3) * 8192;
#pragma unroll
        for (int kk = 0; kk < 2; ++kk) {
            int brow = ng * 16 + r16;
            float4 b0 = *(const float4*)(Bb + brow * 256 + (((kk * 8 + 2 * kg)     ^ (brow & 15)) * 16));
            float4 b1 = *(const float4*)(Bb + brow * 256 + (((kk * 8 + 2 * kg + 1) ^ (brow & 15)) * 16));
            uint4 bu = make_uint4(pack_trunc(b0.x, b0.y), pack_trunc(b0.z, b0.w),
                                  pack_trunc(b1.x, b1.y), pack_trunc(b1.z, b1.w));
            short8 B = __builtin_bit_cast(short8, bu);
#pragma unroll
            for (int m = 0; m < 4; ++m) {
                int arow = mg * 64 + m * 16 + r16;
                short8 A = *(const short8*)(Ab + arow * 128 + (((kk * 4 + kg) ^ (arow & 7)) * 16));
                acc[m] = __builtin_amdgcn_mfma_f32_16x16x32_bf16(A, B, acc[m], 0, 0, 0);
            }
        }
    }

    float sd = sd_p[0];
#pragma unroll
    for (int m = 0; m < 4; ++m)
#pragma unroll
        for (int j = 0; j < 4; ++j) {
            int tr = mg * 64 + m * 16 + kg * 4 + j;
            int pos = mt * 128 + tr;
            if (pos < cnt)
                out[(size_t)tok[tr] * H_ + h0 + ng * 16 + r16] = acc[m][j] * sd;
        }
}

extern "C" void kernel_launch(void* const* d_in, const int* in_sizes, int n_in,
                              void* d_out, int out_size, void* d_ws, size_t ws_size,
                              hipStream_t stream) {
    const float* x    = (const float*)d_in[0];
    const int*   eidx = (const int*)d_in[1];
    const float* wgu  = (const float*)d_in[2];   // fp8 values stored as f32
    const float* sgu  = (const float*)d_in[3];
    const float* wd   = (const float*)d_in[4];   // fp8 values stored as f32
    const float* sd   = (const float*)d_in[5];
    float* out = (float*)d_out;

    char* ws = (char*)d_ws;
    int* counts = (int*)ws;                                   // 32 B
    int* bucket = (int*)(ws + 1024);                          // 16 KB
    unsigned short* xg = (unsigned short*)(ws + 32768);       // 1 MB bf16 x
    __hip_bfloat16* hbuf = (__hip_bfloat16*)(ws + 1114112);   // 2.88 MB

    route_cvt<<<256, 256, 0, stream>>>(x, eidx, counts, bucket, xg);
    gemm1<<<dim3(E_ * 4, I_ / 32), 256, 0, stream>>>(xg, wgu, sgu, counts, bucket, hbuf);
    gemm2<<<dim3(E_ * 4, H_ / 32), 256, 0, stream>>>(hbuf, wd, sd, counts, bucket, out);
}

// Round 9
// 116.216 us; speedup vs baseline: 2.0548x; 2.0548x over previous
//
#include <hip/hip_runtime.h>
#include <hip/hip_bf16.h>
#include <stdint.h>

#define E_ 8
#define H_ 1024
#define I_ 2816
#define T_ 512

typedef __attribute__((ext_vector_type(4))) float f32x4;
typedef __attribute__((ext_vector_type(8))) short short8;

typedef __attribute__((address_space(1))) const unsigned GAS;
typedef __attribute__((address_space(3))) unsigned LAS;

__device__ __forceinline__ void dma16(const void* g, void* l) {
    __builtin_amdgcn_global_load_lds((GAS*)g, (LAS*)l, 16, 0, 0);
}
__device__ __forceinline__ unsigned short f2bf(float f) {   // RNE
    return __builtin_bit_cast(unsigned short, __float2bfloat16(f));
}
__device__ __forceinline__ uint32_t pack_rne(float lo, float hi) {
    return (uint32_t)f2bf(lo) | ((uint32_t)f2bf(hi) << 16);
}
// weights hold exact e4m3 values -> bf16 truncation is exact
__device__ __forceinline__ uint32_t pack_trunc(float lo, float hi) {
    return (__builtin_bit_cast(uint32_t, hi) & 0xFFFF0000u) |
           (__builtin_bit_cast(uint32_t, lo) >> 16);
}

#define VM6() asm volatile("s_waitcnt vmcnt(6)" ::: "memory")
#define VM0() asm volatile("s_waitcnt vmcnt(0)" ::: "memory")

// ---- routing + x->bf16 conversion (fused) ----
__global__ __launch_bounds__(256) void route_cvt(const float* __restrict__ x,
                                                 const int* __restrict__ idx,
                                                 int* __restrict__ counts,
                                                 int* __restrict__ bucket,
                                                 unsigned short* __restrict__ xg) {
    int tid = threadIdx.x;
    if (blockIdx.x == 0) {
        if (tid < E_) counts[tid] = 0;
        for (int i = tid; i < E_ * T_; i += 256) bucket[i] = 0;
        __syncthreads();
#pragma unroll
        for (int k = 0; k < 2; ++k) {
            int t = tid + k * 256;
            int e = idx[t];
            int pos = atomicAdd(counts + e, 1);
            bucket[e * T_ + pos] = t;
        }
    }
    int unit = blockIdx.x * 256 + tid;
    const float* xp = x + (size_t)unit * 8;
    float4 a = *(const float4*)xp, b = *(const float4*)(xp + 4);
    uint4 o = make_uint4(pack_rne(a.x, a.y), pack_rne(a.z, a.w),
                         pack_rne(b.x, b.y), pack_rne(b.z, b.w));
    *(uint4*)(xg + (size_t)unit * 8) = o;
}

// ---- GEMM1: 128 tok x 64 f, barrier-free weight streaming ----
// A (x bf16) staged in K-quarters (64KB LDS); weights HBM->reg->MFMA,
// depth-2 static prefetch, 32 K-steps, silu fused in-lane.
__global__ __launch_bounds__(256) void gemm1(const unsigned short* __restrict__ xg,
                                             const float* __restrict__ wgu,
                                             const float* __restrict__ sgu_p,
                                             const int* __restrict__ counts,
                                             const int* __restrict__ bucket,
                                             __hip_bfloat16* __restrict__ hbuf) {
    int e = blockIdx.x;
    int cnt = counts[e];
    int f0 = blockIdx.y * 64;

    __shared__ __align__(16) char sA[64 * 1024 + 512];
    int* tok = (int*)(sA + 64 * 1024);
    int tid = threadIdx.x, w = tid >> 6, lane = tid & 63;
    int r16 = lane & 15, kg = lane >> 4;

    // per-lane weight stream base: gate row f0+w*16+r16, floats [kg*8 ..)
    const float* gp = wgu + (size_t)e * 2 * (size_t)I_ * H_ +
                      (size_t)(f0 + w * 16 + r16) * H_ + kg * 8;
    const float* up = gp + (size_t)I_ * H_;

#define LOADW(NX, GA, GB, UA, UB)                                   \
    do {                                                            \
        const float* p_ = gp + (size_t)(NX) * 32;                   \
        GA = *(const float4*)p_; GB = *(const float4*)(p_ + 4);     \
        const float* q_ = up + (size_t)(NX) * 32;                   \
        UA = *(const float4*)q_; UB = *(const float4*)(q_ + 4);     \
    } while (0)

    float4 g0a, g0b, u0a, u0b, g1a, g1b, u1a, u1b;
    LOADW(0, g0a, g0b, u0a, u0b);        // issued first: HBM latency overlaps setup
    LOADW(1, g1a, g1b, u1a, u1b);

    if (tid < 128) tok[tid] = bucket[e * T_ + tid];
    __syncthreads();

    f32x4 accg[8], accu[8];
#pragma unroll
    for (int m = 0; m < 8; ++m) { accg[m] = (f32x4){0,0,0,0}; accu[m] = (f32x4){0,0,0,0}; }

#define CSTEP(J, GA, GB, UA, UB)                                                        \
    do {                                                                                \
        uint4 bg_ = make_uint4(pack_trunc((GA).x,(GA).y), pack_trunc((GA).z,(GA).w),    \
                               pack_trunc((GB).x,(GB).y), pack_trunc((GB).z,(GB).w));   \
        uint4 bu_ = make_uint4(pack_trunc((UA).x,(UA).y), pack_trunc((UA).z,(UA).w),    \
                               pack_trunc((UB).x,(UB).y), pack_trunc((UB).z,(UB).w));   \
        short8 Bg_ = __builtin_bit_cast(short8, bg_);                                   \
        short8 Bu_ = __builtin_bit_cast(short8, bu_);                                   \
        const char* ab_ = sA + (((J) * 4 + kg) << 11);                                  \
        _Pragma("unroll")                                                               \
        for (int m_ = 0; m_ < 8; ++m_) {                                                \
            short8 A_ = *(const short8*)(ab_ + ((m_ * 16 + r16) << 4));                 \
            accg[m_] = __builtin_amdgcn_mfma_f32_16x16x32_bf16(A_, Bg_, accg[m_],0,0,0);\
            accu[m_] = __builtin_amdgcn_mfma_f32_16x16x32_bf16(A_, Bu_, accu[m_],0,0,0);\
        }                                                                               \
    } while (0)

    for (int q = 0; q < 4; ++q) {
        __syncthreads();                       // quarter q-1 fully consumed
        // stage A quarter: 128 tok x 256 k bf16, layout [slice][tok][16B]
#pragma unroll
        for (int i = 0; i < 16; ++i) {
            int u = tid + i * 256;
            int s = u >> 7, t_ = u & 127;
            uint4 v = *(const uint4*)(xg + (size_t)tok[t_] * H_ + q * 256 + s * 8);
            *(uint4*)(sA + s * 2048 + t_ * 16) = v;
        }
        __syncthreads();                       // quarter q visible (drains vmem)
#pragma unroll
        for (int j = 0; j < 8; j += 2) {
            CSTEP(j, g0a, g0b, u0a, u0b);
            {
                int nx = q * 8 + j + 2; if (nx > 31) nx = 31;
                LOADW(nx, g0a, g0b, u0a, u0b);
            }
            CSTEP(j + 1, g1a, g1b, u1a, u1b);
            {
                int nx = q * 8 + j + 3; if (nx > 31) nx = 31;
                LOADW(nx, g1a, g1b, u1a, u1b);
            }
        }
    }

    // epilogue: silu(g)*u fully in-lane
    float sgu = sgu_p[0];
#pragma unroll
    for (int m = 0; m < 8; ++m)
#pragma unroll
        for (int j = 0; j < 4; ++j) {
            int tr = m * 16 + kg * 4 + j;
            if (tr < cnt) {
                float g = accg[m][j] * sgu;
                float u = accu[m][j] * sgu;
                float hv = (g / (1.f + __expf(-g))) * u;
                hbuf[(size_t)tok[tr] * I_ + f0 + w * 16 + r16] = __float2bfloat16(hv);
            }
        }
#undef CSTEP
#undef LOADW
}

// ---- GEMM2 (r7 verbatim): 64 tok x 16 hcols, BK=128, 22 steps, depth-3 DMA ----
// LDS: A bf16 3x16KB @0 ; B f32 3x8KB @48KB ; tok @72KB
__global__ __launch_bounds__(256) void gemm2(const __hip_bfloat16* __restrict__ hbuf,
                                             const float* __restrict__ wd,
                                             const float* __restrict__ sd_p,
                                             const int* __restrict__ counts,
                                             const int* __restrict__ bucket,
                                             float* __restrict__ out) {
    int e = blockIdx.x >> 1, mt = blockIdx.x & 1;
    int cnt = counts[e];
    if (mt * 64 >= cnt) return;
    int h0 = blockIdx.y * 16;

    __shared__ __align__(16) char smem[72 * 1024 + 256];
    int* tok = (int*)(smem + 72 * 1024);
    int tid = threadIdx.x, w = tid >> 6, lane = tid & 63;
    int r16 = lane & 15, kg = lane >> 4;

    float sd = sd_p[0];
    asm volatile("" :: "v"(sd));

    if (tid < 64) tok[tid] = bucket[e * T_ + mt * 64 + tid];
    __syncthreads();

    const char* hb = (const char*)hbuf;
    const char* srcA[4]; char* dstA[4];
#pragma unroll
    for (int i = 0; i < 4; ++i) {
        int U = (w * 4 + i) * 64 + lane;
        int row = U >> 4, sl = U & 15;
        srcA[i] = hb + (size_t)tok[row] * (I_ * 2) + (size_t)((sl ^ (row & 15)) * 16);
        dstA[i] = smem + (w * 4 + i) * 1024;
    }
    const char* wd_e = (const char*)(wd + (size_t)e * (size_t)H_ * I_);
    const char* srcB[2]; char* dstB[2];
#pragma unroll
    for (int i = 0; i < 2; ++i) {
        int U = (w * 2 + i) * 64 + lane;
        int row = U >> 5, sl = U & 31;
        srcB[i] = wd_e + (size_t)(h0 + row) * ((size_t)I_ * 4) + (size_t)((sl ^ (row & 15)) * 16);
        dstB[i] = smem + 48 * 1024 + (w * 2 + i) * 1024;
    }

#define G2_ISSUE(s, buf)                                                     \
    do {                                                                     \
        _Pragma("unroll")                                                    \
        for (int i = 0; i < 4; ++i) dma16(srcA[i] + (size_t)(s) * 256, dstA[i] + (buf) * 16384); \
        _Pragma("unroll")                                                    \
        for (int i = 0; i < 2; ++i) dma16(srcB[i] + (size_t)(s) * 512, dstB[i] + (buf) * 8192);  \
    } while (0)

    G2_ISSUE(0, 0);
    G2_ISSUE(1, 1);

    f32x4 acc = (f32x4){0, 0, 0, 0};

    for (int t = 0; t < 22; ++t) {
        VM6();
        __builtin_amdgcn_s_barrier();
        int tp = (t + 2 < 22) ? t + 2 : 21;
        G2_ISSUE(tp, (t + 2) % 3);
        const char* Ab = smem + (t % 3) * 16384;
        const char* Bb = smem + 48 * 1024 + (t % 3) * 8192;
#pragma unroll
        for (int kk = 0; kk < 4; ++kk) {
            int bo = r16 * 512 + kk * 128 + kg * 32;
            int sw = r16 << 4;
            float4 b0 = *(float4*)(Bb + (bo ^ sw));
            float4 b1 = *(float4*)(Bb + ((bo + 16) ^ sw));
            uint4 bu = make_uint4(pack_trunc(b0.x, b0.y), pack_trunc(b0.z, b0.w),
                                  pack_trunc(b1.x, b1.y), pack_trunc(b1.z, b1.w));
            short8 B = __builtin_bit_cast(short8, bu);
            int ar = w * 16 + r16;
            short8 A = *(short8*)(Ab + ((ar * 256 + kk * 64 + kg * 16) ^ ((ar & 15) << 4)));
            acc = __builtin_amdgcn_mfma_f32_16x16x32_bf16(A, B, acc, 0, 0, 0);
        }
    }
    VM0();

#pragma unroll
    for (int j = 0; j < 4; ++j) {
        int tr = w * 16 + kg * 4 + j;
        int pos = mt * 64 + tr;
        if (pos < cnt)
            out[(size_t)tok[tr] * H_ + h0 + r16] = acc[j] * sd;
    }
#undef G2_ISSUE
}

extern "C" void kernel_launch(void* const* d_in, const int* in_sizes, int n_in,
                              void* d_out, int out_size, void* d_ws, size_t ws_size,
                              hipStream_t stream) {
    const float* x    = (const float*)d_in[0];
    const int*   eidx = (const int*)d_in[1];
    const float* wgu  = (const float*)d_in[2];   // fp8 values stored as f32
    const float* sgu  = (const float*)d_in[3];
    const float* wd   = (const float*)d_in[4];   // fp8 values stored as f32
    const float* sd   = (const float*)d_in[5];
    float* out = (float*)d_out;

    char* ws = (char*)d_ws;
    int* counts = (int*)ws;                                   // 32 B
    int* bucket = (int*)(ws + 1024);                          // 16 KB
    unsigned short* xg = (unsigned short*)(ws + 32768);       // 1 MB bf16 x
    __hip_bfloat16* hbuf = (__hip_bfloat16*)(ws + 1114112);   // 2.88 MB

    route_cvt<<<256, 256, 0, stream>>>(x, eidx, counts, bucket, xg);
    gemm1<<<dim3(E_, I_ / 64), 256, 0, stream>>>(xg, wgu, sgu, counts, bucket, hbuf);
    gemm2<<<dim3(E_ * 2, H_ / 16), 256, 0, stream>>>(hbuf, wd, sd, counts, bucket, out);
}

// Round 10
// 113.794 us; speedup vs baseline: 2.0985x; 1.0213x over previous
//
#include <hip/hip_runtime.h>
#include <hip/hip_bf16.h>
#include <stdint.h>

#define E_ 8
#define H_ 1024
#define I_ 2816
#define T_ 512

typedef __attribute__((ext_vector_type(4))) float f32x4;
typedef __attribute__((ext_vector_type(8))) short short8;

typedef __attribute__((address_space(1))) const unsigned GAS;
typedef __attribute__((address_space(3))) unsigned LAS;

__device__ __forceinline__ void dma16(const void* g, void* l) {
    __builtin_amdgcn_global_load_lds((GAS*)g, (LAS*)l, 16, 0, 0);
}
__device__ __forceinline__ unsigned short f2bf(float f) {   // RNE
    return __builtin_bit_cast(unsigned short, __float2bfloat16(f));
}
__device__ __forceinline__ uint32_t pack_rne(float lo, float hi) {
    return (uint32_t)f2bf(lo) | ((uint32_t)f2bf(hi) << 16);
}
// weights hold exact e4m3 values -> bf16 truncation is exact
__device__ __forceinline__ uint32_t pack_trunc(float lo, float hi) {
    return (__builtin_bit_cast(uint32_t, hi) & 0xFFFF0000u) |
           (__builtin_bit_cast(uint32_t, lo) >> 16);
}

#define VM2() asm volatile("s_waitcnt vmcnt(2)" ::: "memory")
#define VM6() asm volatile("s_waitcnt vmcnt(6)" ::: "memory")
#define VM0() asm volatile("s_waitcnt vmcnt(0)" ::: "memory")

// ---- routing + x->bf16 conversion (fused) ----
__global__ __launch_bounds__(256) void route_cvt(const float* __restrict__ x,
                                                 const int* __restrict__ idx,
                                                 int* __restrict__ counts,
                                                 int* __restrict__ bucket,
                                                 unsigned short* __restrict__ xg) {
    int tid = threadIdx.x;
    if (blockIdx.x == 0) {
        if (tid < E_) counts[tid] = 0;
        for (int i = tid; i < E_ * T_; i += 256) bucket[i] = 0;
        __syncthreads();
#pragma unroll
        for (int k = 0; k < 2; ++k) {
            int t = tid + k * 256;
            int e = idx[t];
            int pos = atomicAdd(counts + e, 1);
            bucket[e * T_ + pos] = t;
        }
    }
    int unit = blockIdx.x * 256 + tid;
    const float* xp = x + (size_t)unit * 8;
    float4 a = *(const float4*)xp, b = *(const float4*)(xp + 4);
    uint4 o = make_uint4(pack_rne(a.x, a.y), pack_rne(a.z, a.w),
                         pack_rne(b.x, b.y), pack_rne(b.z, b.w));
    *(uint4*)(xg + (size_t)unit * 8) = o;
}

// ---- GEMM1: 128 tok x 16 f-cols, BK=64, 16 steps, all-DMA counted vmcnt(2) ----
// LDS: A bf16 2x16KB @0 ; B f32 3x8KB @32KB ; tok @56KB
__global__ __launch_bounds__(256) void gemm1(const unsigned short* __restrict__ xg,
                                             const float* __restrict__ wgu,
                                             const float* __restrict__ sgu_p,
                                             const int* __restrict__ counts,
                                             const int* __restrict__ bucket,
                                             __hip_bfloat16* __restrict__ hbuf) {
    int e = blockIdx.x;
    int f0 = blockIdx.y * 16;
    int cnt = counts[e];

    __shared__ __align__(16) char smem[56 * 1024 + 512];
    int* tok = (int*)(smem + 56 * 1024);
    int tid = threadIdx.x, w = tid >> 6, lane = tid & 63;
    int r16 = lane & 15, kg = lane >> 4;

    if (tid < 128) tok[tid] = bucket[e * T_ + tid];
    __syncthreads();

    // A dma: 4 instrs/wave; linear LDS unit U=(w*4+i)*64+lane -> t=U>>3, sl=U&7
    // src pre-swizzled: sl ^ (t&7)  (within 128B window)
    const char* xb = (const char*)xg;
    const char* srcA[4]; char* dstA[4];
#pragma unroll
    for (int i = 0; i < 4; ++i) {
        int U = (w * 4 + i) * 64 + lane;
        int t_ = U >> 3, sl = U & 7;
        srcA[i] = xb + (size_t)tok[t_] * 2048 + ((sl ^ (t_ & 7)) * 16);
        dstA[i] = smem + (w * 4 + i) * 1024;
    }
    // B dma: 2 instrs/wave; unit U=(w*2+i)*64+lane -> row=U>>4 (0..31), sl=U&15
    // rows 0..15 gate f0+row, rows 16..31 up I_+f0+row-16; src slot ^ (row&15)
    const char* wbase = (const char*)wgu + (size_t)e * 2 * (size_t)I_ * H_ * 4;
    const char* srcB[2]; char* dstB[2];
#pragma unroll
    for (int i = 0; i < 2; ++i) {
        int U = (w * 2 + i) * 64 + lane;
        int row = U >> 4, sl = U & 15;
        int wr = (row < 16) ? (f0 + row) : (I_ + f0 + row - 16);
        srcB[i] = wbase + (size_t)wr * 4096 + ((sl ^ (row & 15)) * 16);
        dstB[i] = smem + 32 * 1024 + (w * 2 + i) * 1024;
    }

    // prologue order matters for vmcnt: B0 (oldest), A0, B1 (newest kept by vmcnt(2))
#pragma unroll
    for (int i = 0; i < 2; ++i) dma16(srcB[i], dstB[i]);
#pragma unroll
    for (int i = 0; i < 4; ++i) dma16(srcA[i], dstA[i]);
#pragma unroll
    for (int i = 0; i < 2; ++i) dma16(srcB[i] + 256, dstB[i] + 8192);

    f32x4 accg[2], accu[2];
#pragma unroll
    for (int m = 0; m < 2; ++m) { accg[m] = (f32x4){0,0,0,0}; accu[m] = (f32x4){0,0,0,0}; }

    for (int t = 0; t < 16; ++t) {
        VM2();                                   // A(t), B(t) landed; B(t+1) in flight
        __builtin_amdgcn_sched_barrier(0);
        __builtin_amdgcn_s_barrier();            // raw barrier: no vmcnt drain
        int sa = (t + 1 < 16) ? t + 1 : 15;      // clamped tail keeps counts uniform
        int sb = (t + 2 < 16) ? t + 2 : 15;
#pragma unroll
        for (int i = 0; i < 4; ++i)
            dma16(srcA[i] + (size_t)sa * 128, dstA[i] + ((t + 1) & 1) * 16384);
#pragma unroll
        for (int i = 0; i < 2; ++i)
            dma16(srcB[i] + (size_t)sb * 256, dstB[i] + ((t + 2) % 3) * 8192);

        const char* Ab = smem + (t & 1) * 16384;
        const char* Bb = smem + 32 * 1024 + (t % 3) * 8192;
#pragma unroll
        for (int kk = 0; kk < 2; ++kk) {
            int s0 = kk * 8 + kg * 2;
            // gate row r16, up row 16+r16; both have row&15 == r16
            float4 g0 = *(const float4*)(Bb + r16 * 256 + ((s0 ^ r16) * 16));
            float4 g1 = *(const float4*)(Bb + r16 * 256 + (((s0 + 1) ^ r16) * 16));
            float4 u0 = *(const float4*)(Bb + (16 + r16) * 256 + ((s0 ^ r16) * 16));
            float4 u1 = *(const float4*)(Bb + (16 + r16) * 256 + (((s0 + 1) ^ r16) * 16));
            uint4 bg = make_uint4(pack_trunc(g0.x, g0.y), pack_trunc(g0.z, g0.w),
                                  pack_trunc(g1.x, g1.y), pack_trunc(g1.z, g1.w));
            uint4 bu = make_uint4(pack_trunc(u0.x, u0.y), pack_trunc(u0.z, u0.w),
                                  pack_trunc(u1.x, u1.y), pack_trunc(u1.z, u1.w));
            short8 Bg = __builtin_bit_cast(short8, bg);
            short8 Bu = __builtin_bit_cast(short8, bu);
#pragma unroll
            for (int m = 0; m < 2; ++m) {
                int tr = w * 32 + m * 16 + r16;
                short8 A = *(const short8*)(Ab + tr * 128 + (((kk * 4 + kg) ^ (tr & 7)) * 16));
                accg[m] = __builtin_amdgcn_mfma_f32_16x16x32_bf16(A, Bg, accg[m], 0, 0, 0);
                accu[m] = __builtin_amdgcn_mfma_f32_16x16x32_bf16(A, Bu, accu[m], 0, 0, 0);
            }
        }
    }

    // epilogue: silu(g)*u fully in-lane; C: col=r16 (f), row=token
    float sgu = sgu_p[0];
#pragma unroll
    for (int m = 0; m < 2; ++m)
#pragma unroll
        for (int j = 0; j < 4; ++j) {
            int tk = w * 32 + m * 16 + kg * 4 + j;
            if (tk < cnt) {
                float g = accg[m][j] * sgu;
                float u = accu[m][j] * sgu;
                float hv = (g / (1.f + __expf(-g))) * u;
                hbuf[(size_t)tok[tk] * I_ + f0 + r16] = __float2bfloat16(hv);
            }
        }
}

// ---- GEMM2 (r7 verbatim): 64 tok x 16 hcols, BK=128, 22 steps, depth-3 DMA ----
// LDS: A bf16 3x16KB @0 ; B f32 3x8KB @48KB ; tok @72KB
__global__ __launch_bounds__(256) void gemm2(const __hip_bfloat16* __restrict__ hbuf,
                                             const float* __restrict__ wd,
                                             const float* __restrict__ sd_p,
                                             const int* __restrict__ counts,
                                             const int* __restrict__ bucket,
                                             float* __restrict__ out) {
    int e = blockIdx.x >> 1, mt = blockIdx.x & 1;
    int cnt = counts[e];
    if (mt * 64 >= cnt) return;
    int h0 = blockIdx.y * 16;

    __shared__ __align__(16) char smem[72 * 1024 + 256];
    int* tok = (int*)(smem + 72 * 1024);
    int tid = threadIdx.x, w = tid >> 6, lane = tid & 63;
    int r16 = lane & 15, kg = lane >> 4;

    float sd = sd_p[0];
    asm volatile("" :: "v"(sd));

    if (tid < 64) tok[tid] = bucket[e * T_ + mt * 64 + tid];
    __syncthreads();

    const char* hb = (const char*)hbuf;
    const char* srcA[4]; char* dstA[4];
#pragma unroll
    for (int i = 0; i < 4; ++i) {
        int U = (w * 4 + i) * 64 + lane;
        int row = U >> 4, sl = U & 15;
        srcA[i] = hb + (size_t)tok[row] * (I_ * 2) + (size_t)((sl ^ (row & 15)) * 16);
        dstA[i] = smem + (w * 4 + i) * 1024;
    }
    const char* wd_e = (const char*)(wd + (size_t)e * (size_t)H_ * I_);
    const char* srcB[2]; char* dstB[2];
#pragma unroll
    for (int i = 0; i < 2; ++i) {
        int U = (w * 2 + i) * 64 + lane;
        int row = U >> 5, sl = U & 31;
        srcB[i] = wd_e + (size_t)(h0 + row) * ((size_t)I_ * 4) + (size_t)((sl ^ (row & 15)) * 16);
        dstB[i] = smem + 48 * 1024 + (w * 2 + i) * 1024;
    }

#define G2_ISSUE(s, buf)                                                     \
    do {                                                                     \
        _Pragma("unroll")                                                    \
        for (int i = 0; i < 4; ++i) dma16(srcA[i] + (size_t)(s) * 256, dstA[i] + (buf) * 16384); \
        _Pragma("unroll")                                                    \
        for (int i = 0; i < 2; ++i) dma16(srcB[i] + (size_t)(s) * 512, dstB[i] + (buf) * 8192);  \
    } while (0)

    G2_ISSUE(0, 0);
    G2_ISSUE(1, 1);

    f32x4 acc = (f32x4){0, 0, 0, 0};

    for (int t = 0; t < 22; ++t) {
        VM6();
        __builtin_amdgcn_s_barrier();
        int tp = (t + 2 < 22) ? t + 2 : 21;
        G2_ISSUE(tp, (t + 2) % 3);
        const char* Ab = smem + (t % 3) * 16384;
        const char* Bb = smem + 48 * 1024 + (t % 3) * 8192;
#pragma unroll
        for (int kk = 0; kk < 4; ++kk) {
            int bo = r16 * 512 + kk * 128 + kg * 32;
            int sw = r16 << 4;
            float4 b0 = *(float4*)(Bb + (bo ^ sw));
            float4 b1 = *(float4*)(Bb + ((bo + 16) ^ sw));
            uint4 bu = make_uint4(pack_trunc(b0.x, b0.y), pack_trunc(b0.z, b0.w),
                                  pack_trunc(b1.x, b1.y), pack_trunc(b1.z, b1.w));
            short8 B = __builtin_bit_cast(short8, bu);
            int ar = w * 16 + r16;
            short8 A = *(short8*)(Ab + ((ar * 256 + kk * 64 + kg * 16) ^ ((ar & 15) << 4)));
            acc = __builtin_amdgcn_mfma_f32_16x16x32_bf16(A, B, acc, 0, 0, 0);
        }
    }
    VM0();

#pragma unroll
    for (int j = 0; j < 4; ++j) {
        int tr = w * 16 + kg * 4 + j;
        int pos = mt * 64 + tr;
        if (pos < cnt)
            out[(size_t)tok[tr] * H_ + h0 + r16] = acc[j] * sd;
    }
#undef G2_ISSUE
}

extern "C" void kernel_launch(void* const* d_in, const int* in_sizes, int n_in,
                              void* d_out, int out_size, void* d_ws, size_t ws_size,
                              hipStream_t stream) {
    const float* x    = (const float*)d_in[0];
    const int*   eidx = (const int*)d_in[1];
    const float* wgu  = (const float*)d_in[2];   // fp8 values stored as f32
    const float* sgu  = (const float*)d_in[3];
    const float* wd   = (const float*)d_in[4];   // fp8 values stored as f32
    const float* sd   = (const float*)d_in[5];
    float* out = (float*)d_out;

    char* ws = (char*)d_ws;
    int* counts = (int*)ws;                                   // 32 B
    int* bucket = (int*)(ws + 1024);                          // 16 KB
    unsigned short* xg = (unsigned short*)(ws + 32768);       // 1 MB bf16 x
    __hip_bfloat16* hbuf = (__hip_bfloat16*)(ws + 1114112);   // 2.88 MB

    route_cvt<<<256, 256, 0, stream>>>(x, eidx, counts, bucket, xg);
    gemm1<<<dim3(E_, I_ / 16), 256, 0, stream>>>(xg, wgu, sgu, counts, bucket, hbuf);
    gemm2<<<dim3(E_ * 2, H_ / 16), 256, 0, stream>>>(hbuf, wd, sd, counts, bucket, out);
}